// Round 2
// baseline (137.731 us; speedup 1.0000x reference)
//
#include <hip/hip_runtime.h>
#include <hip/hip_bf16.h>

#define N_ROWS 4096
#define TWO_N  8192
#define ZDIM   256
#define INV_T  (1.0f/0.07f)
// exp((s-1)/T) = exp2((s-1) * INV_T * log2(e))
#define EXP_SCALE (INV_T * 1.44269504088896340736f)
#define GRID_BLOCKS 512

typedef __attribute__((ext_vector_type(8))) short bf16x8;   // 8 bf16 in 4 VGPRs
typedef __attribute__((ext_vector_type(4))) float f32x4;

__device__ __forceinline__ void async_load16(const void* g, void* lds_uniform_base) {
  // HW computes LDS dest = (wave-uniform base) + lane*16; pass base WITHOUT lane term.
  __builtin_amdgcn_global_load_lds(
      (const __attribute__((address_space(1))) void*)g,
      (__attribute__((address_space(3))) void*)lds_uniform_base, 16, 0, 0);
}

// ---------------- Kernel A: normalize rows, emit bf16 reps, fp32 pos, zero rowsum+counter
__global__ __launch_bounds__(256) void normalize_kernel(
    const float* __restrict__ z1, const float* __restrict__ z2,
    __hip_bfloat16* __restrict__ reps, float* __restrict__ pos,
    float* __restrict__ rowsum, int* __restrict__ counter) {
  const int b = blockIdx.x;
  const int t = threadIdx.x;
  const float x1 = z1[b * ZDIM + t];
  const float x2 = z2[b * ZDIM + t];
  float s1 = x1 * x1, s2 = x2 * x2, s3 = x1 * x2;
  #pragma unroll
  for (int m = 1; m < 64; m <<= 1) {
    s1 += __shfl_xor(s1, m, 64);
    s2 += __shfl_xor(s2, m, 64);
    s3 += __shfl_xor(s3, m, 64);
  }
  __shared__ float red[3][4];
  const int w = t >> 6, l = t & 63;
  if (l == 0) { red[0][w] = s1; red[1][w] = s2; red[2][w] = s3; }
  __syncthreads();
  const float n1 = red[0][0] + red[0][1] + red[0][2] + red[0][3];
  const float n2 = red[1][0] + red[1][1] + red[1][2] + red[1][3];
  const float dt = red[2][0] + red[2][1] + red[2][2] + red[2][3];
  const float inv1 = 1.0f / fmaxf(sqrtf(n1), 1e-12f);
  const float inv2 = 1.0f / fmaxf(sqrtf(n2), 1e-12f);
  reps[b * ZDIM + t]            = __float2bfloat16(x1 * inv1);
  reps[(b + N_ROWS) * ZDIM + t] = __float2bfloat16(x2 * inv2);
  if (t == 0) {
    pos[b] = dt * inv1 * inv2;
    rowsum[b] = 0.0f;
    rowsum[b + N_ROWS] = 0.0f;
    if (b == 0) counter[0] = 0;
  }
}

// ---------------- Kernel B: triangular flash row-sums of exp((sim-1)/T) + fused loss ----
// sim is symmetric: compute each unordered 128x128 tile-pair once. Row-tile i handles
// distances d=0..31 (plus d=32 for i<32): j=(i+d)&63. Off-diag tiles contribute row-sums
// to rows of tile i AND column-sums to rows of tile j. Diag tile (d=0) is self-complete
// (mask j==i inline) and reads both operands from Alds (no staging).
// Grid (64 row-tiles, 8 chunks of 4 distances). 512 blocks = exactly 2/CU at 80KB LDS.
// Last block to finish (device-scope counter) reduces rowsum+pos -> loss (fused epilogue).
__global__ __launch_bounds__(256, 2) void simsum_kernel(
    const __hip_bfloat16* __restrict__ reps, float* __restrict__ rowsum,
    const float* __restrict__ pos, int* __restrict__ counter,
    float* __restrict__ out) {
  __shared__ __align__(16) __hip_bfloat16 Alds[128 * 256];  // 64 KB
  __shared__ __align__(16) __hip_bfloat16 Blds[128 * 64];   // 16 KB (total exactly 80 KB)

  const int tid  = threadIdx.x;
  const int lane = tid & 63;
  const int wave = tid >> 6;
  const int wm = wave >> 1, wn = wave & 1;   // 2x2 wave grid
  const int quad = lane >> 4;                // 0..3
  const int l16  = lane & 15;
  const int itile = blockIdx.x;              // row tile 0..63
  const int chunk = blockIdx.y;              // distance chunk 0..7
  const int rowBase = itile * 128;
  const char* gbase = (const char*)reps;

  // Stage A tile: rows [rowBase, rowBase+128), full K=256.
  // LDS 16B-chunk c holds global chunk with low-3-bits XOR'd by row (conflict-min b128 reads)
  #pragma unroll
  for (int p = 0; p < 16; ++p) {
    const int cbase = p * 256 + (wave << 6);
    const int c = cbase + lane;
    const int row = c >> 5;                 // 32 chunks per 512B row
    const int ch = (c & 31) ^ (row & 7);
    const int gofs = ((rowBase + row) * ZDIM + ch * 8) * 2;
    async_load16(gbase + gofs, (char*)Alds + cbase * 16);
  }
  __syncthreads();  // drains A's global_load_lds (vmcnt(0) before s_barrier)

  int dlist[5];
  int nd = 0;
  for (int q = 0; q < 4; ++q) dlist[nd++] = 4 * chunk + q;
  if (chunk == 0 && itile < 32) dlist[nd++] = 32;  // wraparound pair {i, i+32} once

  float rowpart[16];
  #pragma unroll
  for (int i = 0; i < 16; ++i) rowpart[i] = 0.0f;

  const f32x4 zero4 = {0.0f, 0.0f, 0.0f, 0.0f};

  for (int td = 0; td < nd; ++td) {
    const int d = dlist[td];
    const int jtile = (itile + d) & 63;
    const int colBase = jtile * 128;
    const bool diag = (d == 0);

    f32x4 acc[4][4];
    #pragma unroll
    for (int mi = 0; mi < 4; ++mi)
      #pragma unroll
      for (int ni = 0; ni < 4; ++ni) acc[mi][ni] = zero4;

    for (int kc = 0; kc < 4; ++kc) {
      if (!diag) {
        // stage B chunk: rows [colBase, +128), k in [kc*64, +64)
        #pragma unroll
        for (int p = 0; p < 4; ++p) {
          const int cbase = p * 256 + (wave << 6);
          const int c = cbase + lane;
          const int row = c >> 3;               // 8 chunks per 128B row
          const int ch = (c & 7) ^ (row & 7);
          const int gofs = ((colBase + row) * ZDIM + kc * 64 + ch * 8) * 2;
          async_load16(gbase + gofs, (char*)Blds + cbase * 16);
        }
        __syncthreads();
      }

      #pragma unroll
      for (int kk2 = 0; kk2 < 2; ++kk2) {
        bf16x8 afrag[4], bfrag[4];
        #pragma unroll
        for (int mi = 0; mi < 4; ++mi) {
          const int m = wm * 64 + mi * 16 + l16;
          const int ch = kc * 8 + kk2 * 4 + quad;           // chunk in [0,32)
          afrag[mi] = *(const bf16x8*)((const char*)Alds + (m * 32 + (ch ^ (m & 7))) * 16);
        }
        #pragma unroll
        for (int ni = 0; ni < 4; ++ni) {
          const int n = wn * 64 + ni * 16 + l16;
          if (diag) {
            const int ch = kc * 8 + kk2 * 4 + quad;         // read B operand from Alds
            bfrag[ni] = *(const bf16x8*)((const char*)Alds + (n * 32 + (ch ^ (n & 7))) * 16);
          } else {
            const int ch = kk2 * 4 + quad;                  // chunk in [0,8)
            bfrag[ni] = *(const bf16x8*)((const char*)Blds + (n * 8 + (ch ^ (n & 7))) * 16);
          }
        }
        #pragma unroll
        for (int mi = 0; mi < 4; ++mi)
          #pragma unroll
          for (int ni = 0; ni < 4; ++ni)
            acc[mi][ni] = __builtin_amdgcn_mfma_f32_16x16x32_bf16(
                afrag[mi], bfrag[ni], acc[mi][ni], 0, 0, 0);
      }
      if (!diag) __syncthreads();   // all waves done with Blds before restage
    }

    // Epilogue: e=exp((s-1)/T); rows -> rowpart (accumulated across tiles),
    // cols -> per-tile reduce + atomicAdd (transpose contribution), skip for diag.
    float colpart[4] = {0.0f, 0.0f, 0.0f, 0.0f};
    #pragma unroll
    for (int mi = 0; mi < 4; ++mi) {
      #pragma unroll
      for (int r = 0; r < 4; ++r) {
        const int grow = rowBase + wm * 64 + mi * 16 + quad * 4 + r;
        float s = 0.0f;
        #pragma unroll
        for (int ni = 0; ni < 4; ++ni) {
          const int gcol = colBase + wn * 64 + ni * 16 + l16;
          const float v = acc[mi][ni][r];
          const float e = exp2f((v - 1.0f) * EXP_SCALE);
          if (!diag || grow != gcol) s += e;
          colpart[ni] += e;   // includes diag tile but discarded below
        }
        rowpart[mi * 4 + r] += s;
      }
    }
    if (!diag) {
      #pragma unroll
      for (int ni = 0; ni < 4; ++ni) {
        float v = colpart[ni];
        v += __shfl_xor(v, 16, 64);   // reduce across quads (rows)
        v += __shfl_xor(v, 32, 64);
        if (quad == 0)
          atomicAdd(&rowsum[colBase + wn * 64 + ni * 16 + l16], v);
      }
    }
  }

  // Row-sum reduction: 16 lanes share each row (xor over low 4 lane bits)
  #pragma unroll
  for (int i = 0; i < 16; ++i) {
    float v = rowpart[i];
    v += __shfl_xor(v, 1, 64);
    v += __shfl_xor(v, 2, 64);
    v += __shfl_xor(v, 4, 64);
    v += __shfl_xor(v, 8, 64);
    rowpart[i] = v;
  }
  if (l16 == 0) {
    #pragma unroll
    for (int mi = 0; mi < 4; ++mi)
      #pragma unroll
      for (int r = 0; r < 4; ++r)
        atomicAdd(&rowsum[rowBase + wm * 64 + mi * 16 + quad * 4 + r],
                  rowpart[mi * 4 + r]);
  }

  // ---- fused loss: last block to finish reduces rowsum + pos ----
  __threadfence();        // make this thread's atomics globally visible (drains vmcnt)
  __syncthreads();        // whole block's atomics issued+fenced
  int* flag = (int*)Blds; // Blds free now; reuse as scratch
  if (tid == 0) {
    const int old = __hip_atomic_fetch_add(counter, 1, __ATOMIC_ACQ_REL,
                                           __HIP_MEMORY_SCOPE_AGENT);
    flag[0] = (old == GRID_BLOCKS - 1) ? 1 : 0;
  }
  __syncthreads();
  if (flag[0]) {
    __threadfence();      // acquire: see all other blocks' rowsum atomics
    float slog = 0.0f;
    for (int r = tid; r < TWO_N; r += 256) {
      const float rs = __hip_atomic_load(&rowsum[r], __ATOMIC_RELAXED,
                                         __HIP_MEMORY_SCOPE_AGENT);
      slog += logf(rs);
    }
    float spos = 0.0f;
    for (int r = tid; r < N_ROWS; r += 256) spos += pos[r];
    #pragma unroll
    for (int m = 1; m < 64; m <<= 1) {
      slog += __shfl_xor(slog, m, 64);
      spos += __shfl_xor(spos, m, 64);
    }
    float* red = (float*)Blds + 8;
    if (lane == 0) { red[wave] = slog; red[4 + wave] = spos; }
    __syncthreads();
    if (tid == 0) {
      const float tl = red[0] + red[1] + red[2] + red[3];
      const float tp = red[4] + red[5] + red[6] + red[7];
      // loss = 1/T + mean(log rowsum) - (1/T)*mean(pos over 2N; each pos twice)
      out[0] = INV_T + tl / (float)TWO_N - tp * INV_T / (float)N_ROWS;
    }
  }
}

extern "C" void kernel_launch(void* const* d_in, const int* in_sizes, int n_in,
                              void* d_out, int out_size, void* d_ws, size_t ws_size,
                              hipStream_t stream) {
  const float* z1 = (const float*)d_in[0];
  const float* z2 = (const float*)d_in[1];
  __hip_bfloat16* reps = (__hip_bfloat16*)d_ws;                       // 8192*256*2 = 4 MB
  float* rowsum = (float*)((char*)d_ws + (size_t)TWO_N * ZDIM * 2);   // 32 KB
  float* pos = rowsum + TWO_N;                                        // 16 KB
  int* counter = (int*)(pos + N_ROWS);                                // 4 B

  normalize_kernel<<<N_ROWS, 256, 0, stream>>>(z1, z2, reps, pos, rowsum, counter);
  simsum_kernel<<<dim3(64, 8), 256, 0, stream>>>(reps, rowsum, pos, counter,
                                                 (float*)d_out);
}

// Round 4
// 100.513 us; speedup vs baseline: 1.3703x; 1.3703x over previous
//
#include <hip/hip_runtime.h>
#include <hip/hip_bf16.h>

#define N_ROWS 4096
#define TWO_N  8192
#define ZDIM   256
#define INV_T  (1.0f/0.07f)
// exp((s-1)/T) = exp2((s-1) * INV_T * log2(e))
#define EXP_SCALE (INV_T * 1.44269504088896340736f)

typedef __attribute__((ext_vector_type(8))) short bf16x8;   // 8 bf16 in 4 VGPRs
typedef __attribute__((ext_vector_type(4))) float f32x4;

__device__ __forceinline__ void async_load16(const void* g, void* lds_uniform_base) {
  // HW computes LDS dest = (wave-uniform base) + lane*16; pass base WITHOUT lane term.
  __builtin_amdgcn_global_load_lds(
      (const __attribute__((address_space(1))) void*)g,
      (__attribute__((address_space(3))) void*)lds_uniform_base, 16, 0, 0);
}

// ---------------- Kernel A: normalize rows -> bf16 reps, fp32 pos; init out=1/T --------
__global__ __launch_bounds__(256) void normalize_kernel(
    const float* __restrict__ z1, const float* __restrict__ z2,
    __hip_bfloat16* __restrict__ reps, float* __restrict__ pos,
    float* __restrict__ out) {
  const int b = blockIdx.x;
  const int t = threadIdx.x;
  const float x1 = z1[b * ZDIM + t];
  const float x2 = z2[b * ZDIM + t];
  float s1 = x1 * x1, s2 = x2 * x2, s3 = x1 * x2;
  #pragma unroll
  for (int m = 1; m < 64; m <<= 1) {
    s1 += __shfl_xor(s1, m, 64);
    s2 += __shfl_xor(s2, m, 64);
    s3 += __shfl_xor(s3, m, 64);
  }
  __shared__ float red[3][4];
  const int w = t >> 6, l = t & 63;
  if (l == 0) { red[0][w] = s1; red[1][w] = s2; red[2][w] = s3; }
  __syncthreads();
  const float n1 = red[0][0] + red[0][1] + red[0][2] + red[0][3];
  const float n2 = red[1][0] + red[1][1] + red[1][2] + red[1][3];
  const float dt = red[2][0] + red[2][1] + red[2][2] + red[2][3];
  const float inv1 = 1.0f / fmaxf(sqrtf(n1), 1e-12f);
  const float inv2 = 1.0f / fmaxf(sqrtf(n2), 1e-12f);
  reps[b * ZDIM + t]            = __float2bfloat16(x1 * inv1);
  reps[(b + N_ROWS) * ZDIM + t] = __float2bfloat16(x2 * inv2);
  if (t == 0) {
    pos[b] = dt * inv1 * inv2;
    if (b == 0) out[0] = INV_T;   // reduce_kernel atomically adds partials onto this
  }
}

// ---------------- Kernel B: triangular flash row/col partial sums, ZERO atomics ---------
// sim symmetric: each unordered 128x128 tile-pair computed once. Row-tile i, chunk c:
//   c==0: d = {0(diag),1,2,3} (+32 if i<32);  c>0: d = {4c..4c+3};  j = (i+d)&63.
// Row sums -> rowscratch[i][c][128] (reg-accumulated; wn-halves merged via LDS at end —
// BOTH wn waves cover the same rows, a plain per-wave store would race/drop half!).
// Column sums -> colscratch[j][d-1][128], each slot written by exactly ONE block
// (plain stores, no atomics, nothing on the vmcnt/barrier critical path).
// Grid (64,8) = 512 blocks = exactly 2/CU at 80KB LDS.
__global__ __launch_bounds__(256, 2) void simsum_kernel(
    const __hip_bfloat16* __restrict__ reps,
    float* __restrict__ rowscratch,   // [64][8][128]
    float* __restrict__ colscratch) { // [64][32][128]
  __shared__ __align__(16) __hip_bfloat16 Alds[128 * 256];  // 64 KB
  __shared__ __align__(16) __hip_bfloat16 Blds[128 * 64];   // 16 KB (total exactly 80 KB)

  const int tid  = threadIdx.x;
  const int lane = tid & 63;
  const int wave = tid >> 6;
  const int wm = wave >> 1, wn = wave & 1;   // 2x2 wave grid
  const int quad = lane >> 4;                // 0..3
  const int l16  = lane & 15;
  const int itile = blockIdx.x;              // row tile 0..63
  const int chunk = blockIdx.y;              // distance chunk 0..7
  const int rowBase = itile * 128;
  const char* gbase = (const char*)reps;

  // Stage A tile: rows [rowBase, rowBase+128), full K=256.
  // LDS 16B-chunk c holds global chunk with low-3-bits XOR'd by row (conflict-min b128 reads)
  #pragma unroll
  for (int p = 0; p < 16; ++p) {
    const int cbase = p * 256 + (wave << 6);
    const int c = cbase + lane;
    const int row = c >> 5;                 // 32 chunks per 512B row
    const int ch = (c & 31) ^ (row & 7);
    const int gofs = ((rowBase + row) * ZDIM + ch * 8) * 2;
    async_load16(gbase + gofs, (char*)Alds + cbase * 16);
  }
  __syncthreads();  // drains A's global_load_lds (needed before diag tile's Alds reads)

  const int nd = (chunk == 0) ? ((itile < 32) ? 5 : 4) : 4;

  float rowpart[16];
  #pragma unroll
  for (int i = 0; i < 16; ++i) rowpart[i] = 0.0f;

  const f32x4 zero4 = {0.0f, 0.0f, 0.0f, 0.0f};
  float* colred = (float*)Blds;   // [2][128] overlay, used only in epilogue

  for (int td = 0; td < nd; ++td) {
    const int d = (chunk == 0) ? ((td == 4) ? 32 : td) : (chunk * 4 + td);
    const int jtile = (itile + d) & 63;
    const int colBase = jtile * 128;
    const bool diag = (d == 0);

    f32x4 acc[4][4];
    #pragma unroll
    for (int mi = 0; mi < 4; ++mi)
      #pragma unroll
      for (int ni = 0; ni < 4; ++ni) acc[mi][ni] = zero4;

    for (int kc = 0; kc < 4; ++kc) {
      if (!diag) {
        // stage B chunk: rows [colBase, +128), k in [kc*64, +64)
        #pragma unroll
        for (int p = 0; p < 4; ++p) {
          const int cbase = p * 256 + (wave << 6);
          const int c = cbase + lane;
          const int row = c >> 3;               // 8 chunks per 128B row
          const int ch = (c & 7) ^ (row & 7);
          const int gofs = ((colBase + row) * ZDIM + kc * 64 + ch * 8) * 2;
          async_load16(gbase + gofs, (char*)Blds + cbase * 16);
        }
        __syncthreads();
      }

      #pragma unroll
      for (int kk2 = 0; kk2 < 2; ++kk2) {
        bf16x8 afrag[4], bfrag[4];
        #pragma unroll
        for (int mi = 0; mi < 4; ++mi) {
          const int m = wm * 64 + mi * 16 + l16;
          const int ch = kc * 8 + kk2 * 4 + quad;           // chunk in [0,32)
          afrag[mi] = *(const bf16x8*)((const char*)Alds + (m * 32 + (ch ^ (m & 7))) * 16);
        }
        #pragma unroll
        for (int ni = 0; ni < 4; ++ni) {
          const int n = wn * 64 + ni * 16 + l16;
          if (diag) {
            const int ch = kc * 8 + kk2 * 4 + quad;         // read B operand from Alds
            bfrag[ni] = *(const bf16x8*)((const char*)Alds + (n * 32 + (ch ^ (n & 7))) * 16);
          } else {
            const int ch = kk2 * 4 + quad;                  // chunk in [0,8)
            bfrag[ni] = *(const bf16x8*)((const char*)Blds + (n * 8 + (ch ^ (n & 7))) * 16);
          }
        }
        #pragma unroll
        for (int mi = 0; mi < 4; ++mi)
          #pragma unroll
          for (int ni = 0; ni < 4; ++ni)
            acc[mi][ni] = __builtin_amdgcn_mfma_f32_16x16x32_bf16(
                afrag[mi], bfrag[ni], acc[mi][ni], 0, 0, 0);
      }
      if (!diag) __syncthreads();   // all waves done with Blds before restage
    }

    // Epilogue: e = exp((s-1)/T). Rows -> rowpart (regs, accumulated across tiles).
    // Cols (off-diag only) -> LDS combine -> one plain store per element, no atomics.
    float colpart[4] = {0.0f, 0.0f, 0.0f, 0.0f};
    #pragma unroll
    for (int mi = 0; mi < 4; ++mi) {
      #pragma unroll
      for (int r = 0; r < 4; ++r) {
        const int grow = rowBase + wm * 64 + mi * 16 + quad * 4 + r;
        float s = 0.0f;
        #pragma unroll
        for (int ni = 0; ni < 4; ++ni) {
          const int gcol = colBase + wn * 64 + ni * 16 + l16;
          const float v = acc[mi][ni][r];
          const float e = exp2f((v - 1.0f) * EXP_SCALE);
          if (!diag || grow != gcol) s += e;
          colpart[ni] += e;
        }
        rowpart[mi * 4 + r] += s;
      }
    }
    if (!diag) {
      #pragma unroll
      for (int ni = 0; ni < 4; ++ni) {
        float v = colpart[ni];
        v += __shfl_xor(v, 16, 64);   // reduce across the 4 quads (rows of the frag)
        v += __shfl_xor(v, 32, 64);
        if (quad == 0) colred[wm * 128 + wn * 64 + ni * 16 + l16] = v;
      }
      __syncthreads();
      if (tid < 128) {
        const float v = colred[tid] + colred[128 + tid];
        colscratch[(jtile * 32 + (d - 1)) * 128 + tid] = v;   // slot owned by this block
      }
      __syncthreads();  // colred region is reused as Blds by the next tile's staging
    }
  }

  // Row partials: shfl over the 16 column-lanes, then merge the two wn-half waves
  // (same rows, different column halves) through LDS — plain per-wave stores would race.
  #pragma unroll
  for (int i = 0; i < 16; ++i) {
    float v = rowpart[i];
    v += __shfl_xor(v, 1, 64);
    v += __shfl_xor(v, 2, 64);
    v += __shfl_xor(v, 4, 64);
    v += __shfl_xor(v, 8, 64);
    rowpart[i] = v;
  }
  float* rowred = (float*)Blds;   // [2][128] overlay; Blds free after last tile
  __syncthreads();
  if (l16 == 0) {
    #pragma unroll
    for (int mi = 0; mi < 4; ++mi)
      #pragma unroll
      for (int r = 0; r < 4; ++r)
        rowred[wn * 128 + wm * 64 + mi * 16 + quad * 4 + r] = rowpart[mi * 4 + r];
  }
  __syncthreads();
  if (tid < 128)
    rowscratch[(itile * 8 + chunk) * 128 + tid] = rowred[tid] + rowred[128 + tid];
}

// ---------------- Kernel C: gather 40 partials per row, logf, add partial loss ----------
// Grid 64 blocks: block j handles rows [j*128, +128) and pos[j*64, +64).
// out was pre-set to 1/T by normalize; each block atomicAdds its partial (64 atomics).
__global__ __launch_bounds__(256) void reduce_kernel(
    const float* __restrict__ rowscratch, const float* __restrict__ colscratch,
    const float* __restrict__ pos, float* __restrict__ out) {
  const int j = blockIdx.x;
  const int tid = threadIdx.x;
  float v = 0.0f;
  if (tid < 128) {
    float s = 0.0f;
    #pragma unroll
    for (int c = 0; c < 8; ++c) s += rowscratch[(j * 8 + c) * 128 + tid];
    const int ns = (j < 32) ? 31 : 32;   // j<32: the d=32 pair arrived via rowscratch side
    for (int si = 0; si < ns; ++si) s += colscratch[(j * 32 + si) * 128 + tid];
    v = logf(s) * (1.0f / (float)TWO_N);
  } else if (tid < 192) {
    v = -pos[j * 64 + (tid - 128)] * (INV_T / (float)N_ROWS);
  }
  #pragma unroll
  for (int m = 1; m < 64; m <<= 1) v += __shfl_xor(v, m, 64);
  __shared__ float red[4];
  if ((tid & 63) == 0) red[tid >> 6] = v;
  __syncthreads();
  if (tid == 0) atomicAdd(out, red[0] + red[1] + red[2] + red[3]);
}

extern "C" void kernel_launch(void* const* d_in, const int* in_sizes, int n_in,
                              void* d_out, int out_size, void* d_ws, size_t ws_size,
                              hipStream_t stream) {
  const float* z1 = (const float*)d_in[0];
  const float* z2 = (const float*)d_in[1];
  char* ws = (char*)d_ws;
  __hip_bfloat16* reps = (__hip_bfloat16*)ws;              // 8192*256*2 = 4 MB
  size_t off = (size_t)TWO_N * ZDIM * 2;
  float* pos = (float*)(ws + off);        off += N_ROWS * 4;        // 16 KB
  float* rowscratch = (float*)(ws + off); off += 64 * 8 * 128 * 4;  // 256 KB
  float* colscratch = (float*)(ws + off); off += 64 * 32 * 128 * 4; // 1 MB

  normalize_kernel<<<N_ROWS, 256, 0, stream>>>(z1, z2, reps, pos, (float*)d_out);
  simsum_kernel<<<dim3(64, 8), 256, 0, stream>>>(reps, rowscratch, colscratch);
  reduce_kernel<<<64, 256, 0, stream>>>(rowscratch, colscratch, pos, (float*)d_out);
}